// Round 6
// baseline (284.077 us; speedup 1.0000x reference)
//
#include <hip/hip_runtime.h>
#include <cstdint>
#include <cstddef>

#define C_CH  384
#define HW    56
#define PLANE 3136
#define KK    31
#define PAD   15

typedef _Float16 f16x8 __attribute__((ext_vector_type(8)));
typedef float    f32x16 __attribute__((ext_vector_type(16)));
typedef uint32_t u32x4 __attribute__((ext_vector_type(4)));
typedef uint64_t u64x2 __attribute__((ext_vector_type(2)));

// LDS geometry (bytes). Plane rows are 256B (128 halfs): XOR swizzle (bits 4-6)
// stays in-row (R4 lesson).
#define ROWB   256
#define NROWS  94                  // rows 0..85 padded image, 86..93 zero
#define PLSZ   (NROWS*ROWB)        // 24064 per plane
#define LDSG   (2*PLSZ)            // 48128 — global-B kernel (planes only)
// fallback (R5) kernel keeps weights in LDS:
#define WE_OFF (2*PLSZ)
#define WO_OFF (WE_OFF + 31*192)
#define LDS_BYTES (WO_OFF + 31*192)  // 60032

static __device__ __forceinline__ uint32_t pack_h2(float a, float b) {
    return __builtin_bit_cast(uint32_t, __builtin_amdgcn_cvt_pkrtz(a, b));
}

// ---------------- weight merge + BN fold (fp32, stride-32 rows) ----------------
__global__ void prep_weights(const float* __restrict__ lk_w,
                             const float* __restrict__ lk_g, const float* __restrict__ lk_b,
                             const float* __restrict__ lk_m, const float* __restrict__ lk_v,
                             const float* __restrict__ sk_w,
                             const float* __restrict__ sk_g, const float* __restrict__ sk_b,
                             const float* __restrict__ sk_m, const float* __restrict__ sk_v,
                             float* __restrict__ wm, float* __restrict__ bias) {
    const int c = blockIdx.x;
    const float s1 = lk_g[c] / sqrtf(lk_v[c] + 1e-5f);
    const float s2 = sk_g[c] / sqrtf(sk_v[c] + 1e-5f);
    if (threadIdx.x == 0)
        bias[c] = (lk_b[c] - lk_m[c] * s1) + (sk_b[c] - sk_m[c] * s2);
    for (int i = threadIdx.x; i < KK * 32; i += blockDim.x) {
        const int ky = i >> 5, kx = i & 31;
        float w = 0.f;
        if (kx < KK) {
            w = lk_w[c * (KK*KK) + ky * KK + kx] * s1;
            if (ky >= 13 && ky <= 17 && kx >= 13 && kx <= 17)
                w += sk_w[c * 25 + (ky - 13) * 5 + (kx - 13)] * s2;
        }
        wm[c * (KK*32) + i] = w;
    }
}

// ---------------- prebuild per-lane B-fragments (Toeplitz windows) ----------------
// entry [c][ky][cc][lane] = 8 halfs Wm[ky, s0..s0+7], s0 = 16cc+8hi+31-col-32
// (zero outside [0,30]). Image-independent, N-tile-independent.
__global__ void prep_frags(const float* __restrict__ wm, u32x4* __restrict__ btab) {
    const int c = blockIdx.x, tid = threadIdx.x;
    const int cc = tid >> 6, lane = tid & 63;
    const int hi = lane >> 5, col = lane & 31;
    const int s0 = 16*cc + 8*hi + 31 - col - 32;
    const float* wr = wm + c * (KK*32);
    for (int ky = 0; ky < KK; ++ky) {
        f16x8 f;
        #pragma unroll
        for (int e = 0; e < 8; ++e) {
            const int idx = s0 + e;
            const float v = (idx >= 0 && idx < KK) ? wr[ky*32 + idx] : 0.f;
            f[e] = (_Float16)v;
        }
        btab[((size_t)c*KK + ky)*256 + tid] = __builtin_bit_cast(u32x4, f);
    }
}

// ---------------- main: Toeplitz MFMA, B from global table ----------------
// Block = (channel, 2 planes). Wave hp owns h-tile h0=16*hp (M=32 = 2 planes x
// 16 rows) x BOTH N-tiles {w 0..31, 32..63}. Per ky: 4 B-frags (global dwordx4,
// double-buffered), 6 A-chunks (swizzled ds_read_b128, chunks q=0..5 at j=16q;
// nt0 uses q=cc, nt1 uses q=2+cc — middle chunks shared), 8 MFMAs.
__global__ __launch_bounds__(256, 2) void dw31_mfma_g(const float* __restrict__ x,
                                                      const u32x4* __restrict__ btab,
                                                      const float* __restrict__ bias,
                                                      float* __restrict__ out) {
    __shared__ __align__(16) uint8_t lds8[LDSG];
    const int c = blockIdx.x, ng = blockIdx.y;
    const int tid = threadIdx.x, hp = tid >> 6, lane = tid & 63;
    const int col = lane & 31, hi = lane >> 5;

    {   // zero planes (halo + tail rows)
        uint4 z = make_uint4(0u,0u,0u,0u);
        uint4* p = (uint4*)lds8;
        for (int i = tid; i < LDSG/16; i += 256) p[i] = z;
    }
    __syncthreads();
    // stage 2 planes f32 -> f16 (swizzled); LDS col j = x col (j-16), row rl = x row (rl-15)
    for (int i = tid; i < 2*784; i += 256) {
        const int nn = (i >= 784);
        const int ii = i - nn*784;
        const int r = ii / 14, q = ii - r*14;
        const float4 v = ((const float4*)(x + ((size_t)((ng*2+nn)*C_CH + c))*PLANE))[ii];
        const int rl = r + PAD;
        int byte0 = nn*PLSZ + rl*ROWB + 2*(16 + 4*q);
        byte0 ^= (rl & 14) << 3;
        uint2 h;
        h.x = pack_h2(v.x, v.y);
        h.y = pack_h2(v.z, v.w);
        *(uint2*)(lds8 + byte0) = h;
    }
    __syncthreads();

    const int nn_a = col >> 4, hr = col & 15, h0 = hp * 16;
    const u32x4* bt = btab + (size_t)c*KK*256 + lane;   // + ky*256 + cc*64

    f32x16 acc0 = {0.f}, acc1 = {0.f};
    u32x4 b0 = bt[0], b1 = bt[64], b2 = bt[128], b3 = bt[192];

    #pragma unroll 1
    for (int ky = 0; ky < KK; ++ky) {
        const int kyn = (ky < KK-1) ? ky + 1 : ky;
        const u32x4* btn = bt + kyn*256;
        u32x4 n0 = btn[0], n1 = btn[64], n2 = btn[128], n3 = btn[192];

        const int rl = h0 + hr + ky;
        const int sw = (rl & 14) << 3;
        const int base = nn_a*PLSZ + rl*ROWB + 16*hi;
        u64x2 a0 = *(const u64x2*)(lds8 + ((base      ) ^ sw));
        u64x2 a1 = *(const u64x2*)(lds8 + ((base +  32) ^ sw));
        u64x2 a2 = *(const u64x2*)(lds8 + ((base +  64) ^ sw));
        u64x2 a3 = *(const u64x2*)(lds8 + ((base +  96) ^ sw));
        u64x2 a4 = *(const u64x2*)(lds8 + ((base + 128) ^ sw));
        u64x2 a5 = *(const u64x2*)(lds8 + ((base + 160) ^ sw));

        acc0 = __builtin_amdgcn_mfma_f32_32x32x16_f16(
            __builtin_bit_cast(f16x8, a0), __builtin_bit_cast(f16x8, b0), acc0, 0, 0, 0);
        acc1 = __builtin_amdgcn_mfma_f32_32x32x16_f16(
            __builtin_bit_cast(f16x8, a2), __builtin_bit_cast(f16x8, b0), acc1, 0, 0, 0);
        acc0 = __builtin_amdgcn_mfma_f32_32x32x16_f16(
            __builtin_bit_cast(f16x8, a1), __builtin_bit_cast(f16x8, b1), acc0, 0, 0, 0);
        acc1 = __builtin_amdgcn_mfma_f32_32x32x16_f16(
            __builtin_bit_cast(f16x8, a3), __builtin_bit_cast(f16x8, b1), acc1, 0, 0, 0);
        acc0 = __builtin_amdgcn_mfma_f32_32x32x16_f16(
            __builtin_bit_cast(f16x8, a2), __builtin_bit_cast(f16x8, b2), acc0, 0, 0, 0);
        acc1 = __builtin_amdgcn_mfma_f32_32x32x16_f16(
            __builtin_bit_cast(f16x8, a4), __builtin_bit_cast(f16x8, b2), acc1, 0, 0, 0);
        acc0 = __builtin_amdgcn_mfma_f32_32x32x16_f16(
            __builtin_bit_cast(f16x8, a3), __builtin_bit_cast(f16x8, b3), acc0, 0, 0, 0);
        acc1 = __builtin_amdgcn_mfma_f32_32x32x16_f16(
            __builtin_bit_cast(f16x8, a5), __builtin_bit_cast(f16x8, b3), acc1, 0, 0, 0);

        b0 = n0; b1 = n1; b2 = n2; b3 = n3;
    }

    // epilogue: C/D layout col=lane&31, m=(reg&3)+8*(reg>>2)+4*hi
    const float bsv = bias[c];
    #pragma unroll
    for (int reg = 0; reg < 16; ++reg) {
        const int mm = (reg & 3) + 8*(reg >> 2) + 4*hi;
        const int nn = mm >> 4, hro = mm & 15;
        const int h = h0 + hro;
        if (h < HW) {
            float* op = out + ((size_t)((ng*2+nn)*C_CH + c))*PLANE + h*HW;
            op[col] = acc0[reg] + bsv;                 // w = col <= 31 < 56
            if (col < 24) op[32 + col] = acc1[reg] + bsv;
        }
    }
}

// ---------------- fallback (R5 verbatim): B-frags gathered from LDS ----------------
__global__ __launch_bounds__(256, 2) void dw31_mfma_l(const float* __restrict__ x,
                                                      const float* __restrict__ wm,
                                                      const float* __restrict__ bias,
                                                      float* __restrict__ out) {
    __shared__ __align__(16) uint8_t lds8[LDS_BYTES];
    const int c  = blockIdx.x;
    const int ng = blockIdx.y;
    const int tid = threadIdx.x;
    const int wid = tid >> 6, lane = tid & 63;
    const int wt = wid & 1, hp = wid >> 1;
    const int col = lane & 31, hi = lane >> 5;

    {
        uint4 z = make_uint4(0u,0u,0u,0u);
        uint4* p = (uint4*)lds8;
        for (int i = tid; i < LDS_BYTES/16; i += 256) p[i] = z;
    }
    __syncthreads();
    for (int i = tid; i < 2*784; i += 256) {
        const int nn = (i >= 784);
        const int ii = i - nn*784;
        const int r = ii / 14, q = ii - r*14;
        const float4 v = ((const float4*)(x + ((size_t)((ng*2+nn)*C_CH + c))*PLANE))[ii];
        const int rl = r + PAD;
        int byte0 = nn*PLSZ + rl*ROWB + 2*(16 + 4*q);
        byte0 ^= (rl & 14) << 3;
        uint2 h;
        h.x = pack_h2(v.x, v.y);
        h.y = pack_h2(v.z, v.w);
        *(uint2*)(lds8 + byte0) = h;
    }
    {
        const float* wrow = wm + c*(KK*32);
        for (int idx = tid; idx < 2*961; idx += 256) {
            const int cp = (idx >= 961);
            const int r2 = idx - cp*961;
            const int ky = r2 / 31, kx = r2 - ky*31;
            const int t = kx + (cp ? 31 : 32);
            const int byte0 = (cp ? WO_OFF : WE_OFF) + ky*192 + 2*t;
            *(_Float16*)(lds8 + byte0) = (_Float16)wrow[ky*32 + kx];
        }
    }
    __syncthreads();

    f32x16 acc0 = {0.f}; f32x16 acc1 = {0.f};
    const int m    = col;
    const int nn_a = m >> 4, hr = m & 15;
    const int h0a  = (hp*2 + 0) * 16;
    const int h0b  = (hp*2 + 1) * 16;
    const int acolbyte = 2*(wt*32 + 8*hi);

    for (int ky = 0; ky < KK; ++ky) {
        f16x8 bf[4];
        #pragma unroll
        for (int cc = 0; cc < 4; ++cc) {
            const int t0 = 16*cc + 8*hi + 31 - col;
            const int off = (t0 & 1) ? (WO_OFF + ((t0 - 1) << 1))
                                     : (WE_OFF + (t0 << 1));
            const uint32_t* wp = (const uint32_t*)(lds8 + ky*192 + off);
            u32x4 u = { wp[0], wp[1], wp[2], wp[3] };
            bf[cc] = __builtin_bit_cast(f16x8, u);
        }
        {
            const int rl = h0a + hr + ky;
            const int sw = (rl & 14) << 3;
            const int base = nn_a*PLSZ + rl*ROWB + acolbyte;
            #pragma unroll
            for (int cc = 0; cc < 4; ++cc) {
                u64x2 u = *(const u64x2*)(lds8 + ((base + 32*cc) ^ sw));
                acc0 = __builtin_amdgcn_mfma_f32_32x32x16_f16(
                    __builtin_bit_cast(f16x8, u), bf[cc], acc0, 0, 0, 0);
            }
        }
        {
            const int rl = h0b + hr + ky;
            const int sw = (rl & 14) << 3;
            const int base = nn_a*PLSZ + rl*ROWB + acolbyte;
            #pragma unroll
            for (int cc = 0; cc < 4; ++cc) {
                u64x2 u = *(const u64x2*)(lds8 + ((base + 32*cc) ^ sw));
                acc1 = __builtin_amdgcn_mfma_f32_32x32x16_f16(
                    __builtin_bit_cast(f16x8, u), bf[cc], acc1, 0, 0, 0);
            }
        }
    }

    const float b = bias[c];
    const int w = wt*32 + col;
    if (w < HW) {
        #pragma unroll
        for (int t = 0; t < 2; ++t) {
            const int h0 = t ? h0b : h0a;
            #pragma unroll
            for (int reg = 0; reg < 16; ++reg) {
                const int mm = (reg & 3) + 8*(reg >> 2) + 4*hi;
                const int nn = mm >> 4, hro = mm & 15;
                const int h = h0 + hro;
                if (h < HW) {
                    const float v = (t ? acc1[reg] : acc0[reg]) + b;
                    out[((size_t)((ng*2+nn)*C_CH + c))*PLANE + h*HW + w] = v;
                }
            }
        }
    }
}

extern "C" void kernel_launch(void* const* d_in, const int* in_sizes, int n_in,
                              void* d_out, int out_size, void* d_ws, size_t ws_size,
                              hipStream_t stream) {
    const float* x    = (const float*)d_in[0];
    const float* lk_w = (const float*)d_in[1];
    const float* lk_g = (const float*)d_in[2];
    const float* lk_b = (const float*)d_in[3];
    const float* lk_m = (const float*)d_in[4];
    const float* lk_v = (const float*)d_in[5];
    const float* sk_w = (const float*)d_in[6];
    const float* sk_g = (const float*)d_in[7];
    const float* sk_b = (const float*)d_in[8];
    const float* sk_m = (const float*)d_in[9];
    const float* sk_v = (const float*)d_in[10];
    float* out = (float*)d_out;

    const size_t table_bytes = (size_t)C_CH * KK * 256 * 16;   // 48.76 MB
    const size_t wm_floats   = (size_t)C_CH * KK * 32;
    const size_t need_g      = table_bytes + (wm_floats + C_CH) * sizeof(float);

    dim3 grid(C_CH, 8);
    if (ws_size >= need_g) {
        u32x4* btab = (u32x4*)d_ws;
        float* wm   = (float*)((uint8_t*)d_ws + table_bytes);
        float* bias = wm + wm_floats;
        prep_weights<<<C_CH, 256, 0, stream>>>(lk_w, lk_g, lk_b, lk_m, lk_v,
                                               sk_w, sk_g, sk_b, sk_m, sk_v, wm, bias);
        prep_frags<<<C_CH, 256, 0, stream>>>(wm, btab);
        dw31_mfma_g<<<grid, 256, 0, stream>>>(x, btab, bias, out);
    } else {
        float* wm   = (float*)d_ws;
        float* bias = wm + wm_floats;
        prep_weights<<<C_CH, 256, 0, stream>>>(lk_w, lk_g, lk_b, lk_m, lk_v,
                                               sk_w, sk_g, sk_b, sk_m, sk_v, wm, bias);
        dw31_mfma_l<<<grid, 256, 0, stream>>>(x, wm, bias, out);
    }
}